// Round 1
// baseline (101.651 us; speedup 1.0000x reference)
//
#include <hip/hip_runtime.h>
#include <math.h>

#define NV 16

__global__ __launch_bounds__(256) void nxro_fused(
    const float* __restrict__ x,
    const float* __restrict__ t_years,
    const float* __restrict__ Lb,      // [5][16][16]
    const float* __restrict__ wq,
    const float* __restrict__ wk,
    const float* __restrict__ wv,
    const float* __restrict__ wo,
    const float* __restrict__ aw,      // [5]
    float* __restrict__ out,
    int Btot)
{
    int b = blockIdx.x * 256 + threadIdx.x;
    if (b >= Btot) return;

    // Wave-uniform scalars: wq.wk and wv.wo (compiler scalarizes the loads).
    float cqk = 0.f, cvo = 0.f;
#pragma unroll
    for (int d = 0; d < 32; ++d) {
        cqk = fmaf(wq[d], wk[d], cqk);
        cvo = fmaf(wv[d], wo[d], cvo);
    }
    cqk *= 0.17677669529663687f;   // 1/sqrt(32)

    // Fourier features. Reduce arg to [0,1) first (t - trunc(t) is exact),
    // keeps __sincosf on the fast path and beats the reference's own f32
    // rounding of 2*pi*t.
    float t = t_years[b];
    float tf = t - truncf(t);
    float ang = 6.28318530717958647692f * tf;
    float s1, c1;
    __sincosf(ang, &s1, &c1);
    float c2 = c1 * c1 - s1 * s1;   // cos(2w t)
    float s2 = 2.f * c1 * s1;       // sin(2w t)

    // Load x row (64B) as 4x float4.
    float xv[NV];
    const float4* xp = reinterpret_cast<const float4*>(x) + (size_t)b * 4;
    float4 q0 = xp[0], q1 = xp[1], q2 = xp[2], q3 = xp[3];
    xv[0]=q0.x; xv[1]=q0.y; xv[2]=q0.z;  xv[3]=q0.w;
    xv[4]=q1.x; xv[5]=q1.y; xv[6]=q1.z;  xv[7]=q1.w;
    xv[8]=q2.x; xv[9]=q2.y; xv[10]=q2.z; xv[11]=q2.w;
    xv[12]=q3.x; xv[13]=q3.y; xv[14]=q3.z; xv[15]=q3.w;

    // dxdt_u = sum_k emb_k * (L_k x)_u ; Lb loads are wave-uniform -> s_load.
    float dx[NV];
#pragma unroll
    for (int u = 0; u < NV; ++u) {
        float a0=0.f, a1=0.f, a2=0.f, a3=0.f, a4=0.f;
#pragma unroll
        for (int v = 0; v < NV; ++v) {
            float q = xv[v];
            a0 = fmaf(Lb[0*256 + u*16 + v], q, a0);
            a1 = fmaf(Lb[1*256 + u*16 + v], q, a1);
            a2 = fmaf(Lb[2*256 + u*16 + v], q, a2);
            a3 = fmaf(Lb[3*256 + u*16 + v], q, a3);
            a4 = fmaf(Lb[4*256 + u*16 + v], q, a4);
        }
        dx[u] = a0 + c1*a1 + s1*a2 + c2*a3 + s2*a4;
    }

    // alpha = sigmoid(emb . alpha_w)
    float z = aw[0] + c1*aw[1] + s1*aw[2] + c2*aw[3] + s2*aw[4];
    float alpha = 1.f / (1.f + __expf(-z));
    float g = alpha * cvo;

    // Attention: rank-1 scores c_qk*x_v*x_u, masked to {u=0, u=1, u=v}.
    float X0 = xv[0], X1 = xv[1];
    float res[NV];
#pragma unroll
    for (int v = 0; v < NV; ++v) {
        float sv = cqk * xv[v];
        float a0 = sv * X0;
        float a1 = sv * X1;
        float s;
        if (v >= 2) {                 // compile-time branch (loop unrolled)
            float av = sv * xv[v];
            float m = fmaxf(fmaxf(a0, a1), av);
            float e0 = __expf(a0 - m), e1 = __expf(a1 - m), ev = __expf(av - m);
            s = (e0*X0 + e1*X1 + ev*xv[v]) / (e0 + e1 + ev);
        } else {                      // rows 0,1: diagonal coincides with cols 0/1
            float m = fmaxf(a0, a1);
            float e0 = __expf(a0 - m), e1 = __expf(a1 - m);
            s = (e0*X0 + e1*X1) / (e0 + e1);
        }
        res[v] = fmaf(g, s, dx[v]);
    }

    float4* op = reinterpret_cast<float4*>(out) + (size_t)b * 4;
    op[0] = make_float4(res[0],  res[1],  res[2],  res[3]);
    op[1] = make_float4(res[4],  res[5],  res[6],  res[7]);
    op[2] = make_float4(res[8],  res[9],  res[10], res[11]);
    op[3] = make_float4(res[12], res[13], res[14], res[15]);
}

extern "C" void kernel_launch(void* const* d_in, const int* in_sizes, int n_in,
                              void* d_out, int out_size, void* d_ws, size_t ws_size,
                              hipStream_t stream)
{
    const float* x  = (const float*)d_in[0];
    const float* t  = (const float*)d_in[1];
    const float* Lb = (const float*)d_in[2];
    const float* wq = (const float*)d_in[3];
    const float* wk = (const float*)d_in[4];
    const float* wv = (const float*)d_in[5];
    const float* wo = (const float*)d_in[6];
    const float* aw = (const float*)d_in[7];
    float* out = (float*)d_out;

    int Btot = in_sizes[1];               // B from t_years
    int grid = (Btot + 255) / 256;
    nxro_fused<<<grid, 256, 0, stream>>>(x, t, Lb, wq, wk, wv, wo, aw, out, Btot);
}

// Round 2
// 101.209 us; speedup vs baseline: 1.0044x; 1.0044x over previous
//
#include <hip/hip_runtime.h>
#include <math.h>

#define NV 16

__global__ __launch_bounds__(256) void nxro_fused(
    const float* __restrict__ x,
    const float* __restrict__ t_years,
    const float* __restrict__ Lb,      // [5][16][16]
    const float* __restrict__ wq,
    const float* __restrict__ wk,
    const float* __restrict__ wv,
    const float* __restrict__ wo,
    const float* __restrict__ aw,      // [5]
    float* __restrict__ out,
    int Btot)
{
    int b = blockIdx.x * 256 + threadIdx.x;
    if (b >= Btot) return;

    // Wave-uniform scalars wq.wk and wv.wo, vectorized loads (8 float4 each pair).
    const float4* wq4 = reinterpret_cast<const float4*>(wq);
    const float4* wk4 = reinterpret_cast<const float4*>(wk);
    const float4* wv4 = reinterpret_cast<const float4*>(wv);
    const float4* wo4 = reinterpret_cast<const float4*>(wo);
    float cqk = 0.f, cvo = 0.f;
#pragma unroll
    for (int d = 0; d < 8; ++d) {
        float4 a = wq4[d], bq = wk4[d], c = wv4[d], e = wo4[d];
        cqk = fmaf(a.x,bq.x, fmaf(a.y,bq.y, fmaf(a.z,bq.z, fmaf(a.w,bq.w, cqk))));
        cvo = fmaf(c.x,e.x,  fmaf(c.y,e.y,  fmaf(c.z,e.z,  fmaf(c.w,e.w,  cvo))));
    }
    cqk *= 0.17677669529663687f;   // 1/sqrt(32)

    // Fourier features; t - trunc(t) is exact, keeps sincos arg small.
    float t = t_years[b];
    float tf = t - truncf(t);
    float ang = 6.28318530717958647692f * tf;
    float s1, c1;
    __sincosf(ang, &s1, &c1);
    float c2 = c1 * c1 - s1 * s1;   // cos(2wt)
    float s2 = 2.f * c1 * s1;       // sin(2wt)

    // x row: 4x float4 (64B coalesced).
    const float4* xp = reinterpret_cast<const float4*>(x) + (size_t)b * 4;
    float4 xq[4] = { xp[0], xp[1], xp[2], xp[3] };
    float xv[NV];
#pragma unroll
    for (int i = 0; i < 4; ++i) {
        xv[4*i+0]=xq[i].x; xv[4*i+1]=xq[i].y; xv[4*i+2]=xq[i].z; xv[4*i+3]=xq[i].w;
    }

    // dxdt_u = sum_k emb_k (L_k x)_u.  Lb read as uniform float4: 320 16B
    // loads (vs 1280 scalar) -> s_load_dwordx4 or L1-broadcast dwordx4.
    const float4* Lb4 = reinterpret_cast<const float4*>(Lb);  // idx k*64 + u*4 + v4
    float dx[NV];
#pragma unroll
    for (int u = 0; u < NV; ++u) {
        float a0=0.f, a1=0.f, a2=0.f, a3=0.f, a4=0.f;
#pragma unroll
        for (int v4 = 0; v4 < 4; ++v4) {
            float4 q = xq[v4];
            float4 l0 = Lb4[0*64 + u*4 + v4];
            float4 l1 = Lb4[1*64 + u*4 + v4];
            float4 l2 = Lb4[2*64 + u*4 + v4];
            float4 l3 = Lb4[3*64 + u*4 + v4];
            float4 l4 = Lb4[4*64 + u*4 + v4];
            a0 = fmaf(l0.x,q.x, fmaf(l0.y,q.y, fmaf(l0.z,q.z, fmaf(l0.w,q.w, a0))));
            a1 = fmaf(l1.x,q.x, fmaf(l1.y,q.y, fmaf(l1.z,q.z, fmaf(l1.w,q.w, a1))));
            a2 = fmaf(l2.x,q.x, fmaf(l2.y,q.y, fmaf(l2.z,q.z, fmaf(l2.w,q.w, a2))));
            a3 = fmaf(l3.x,q.x, fmaf(l3.y,q.y, fmaf(l3.z,q.z, fmaf(l3.w,q.w, a3))));
            a4 = fmaf(l4.x,q.x, fmaf(l4.y,q.y, fmaf(l4.z,q.z, fmaf(l4.w,q.w, a4))));
        }
        dx[u] = a0 + c1*a1 + s1*a2 + c2*a3 + s2*a4;
    }

    // alpha = sigmoid(emb . alpha_w); fold in wv.wo.
    float z = aw[0] + c1*aw[1] + s1*aw[2] + c2*aw[3] + s2*aw[4];
    float alpha = 1.f / (1.f + __expf(-z));
    float g = alpha * cvo;

    // Attention collapses to rank-1: scores[v,u] = cqk*x_v*x_u, mask keeps
    // {u=0, u=1, u=v}; O.wo = (sum_u attn*x_u) * (wv.wo).
    float X0 = xv[0], X1 = xv[1];
    float res[NV];
#pragma unroll
    for (int v = 0; v < NV; ++v) {
        float sv = cqk * xv[v];
        float a0 = sv * X0;
        float a1 = sv * X1;
        float s;
        if (v >= 2) {
            float av = sv * xv[v];
            float m = fmaxf(fmaxf(a0, a1), av);
            float e0 = __expf(a0 - m), e1 = __expf(a1 - m), ev = __expf(av - m);
            s = (e0*X0 + e1*X1 + ev*xv[v]) / (e0 + e1 + ev);
        } else {      // rows 0,1: diagonal coincides with masked cols 0/1
            float m = fmaxf(a0, a1);
            float e0 = __expf(a0 - m), e1 = __expf(a1 - m);
            s = (e0*X0 + e1*X1) / (e0 + e1);
        }
        res[v] = fmaf(g, s, dx[v]);
    }

    float4* op = reinterpret_cast<float4*>(out) + (size_t)b * 4;
    op[0] = make_float4(res[0],  res[1],  res[2],  res[3]);
    op[1] = make_float4(res[4],  res[5],  res[6],  res[7]);
    op[2] = make_float4(res[8],  res[9],  res[10], res[11]);
    op[3] = make_float4(res[12], res[13], res[14], res[15]);
}

extern "C" void kernel_launch(void* const* d_in, const int* in_sizes, int n_in,
                              void* d_out, int out_size, void* d_ws, size_t ws_size,
                              hipStream_t stream)
{
    const float* x  = (const float*)d_in[0];
    const float* t  = (const float*)d_in[1];
    const float* Lb = (const float*)d_in[2];
    const float* wq = (const float*)d_in[3];
    const float* wk = (const float*)d_in[4];
    const float* wv = (const float*)d_in[5];
    const float* wo = (const float*)d_in[6];
    const float* aw = (const float*)d_in[7];
    float* out = (float*)d_out;

    int Btot = in_sizes[1];               // B from t_years
    int grid = (Btot + 255) / 256;
    nxro_fused<<<grid, 256, 0, stream>>>(x, t, Lb, wq, wk, wv, wo, aw, out, Btot);
}